// Round 1
// 110.452 us; speedup vs baseline: 1.0473x; 1.0473x over previous
//
#include <hip/hip_runtime.h>
#include <math.h>

#define NFREQ 10
#define INV2PI 0.15915494309189535f
#define TPB 256
#define FPT 2                          // fragments per thread
#define SCALE_F 1048576.0f             // 2^20 fixed-point scale
#define INV_SCALE 9.5367431640625e-07f // 2^-20

typedef float v2f __attribute__((ext_vector_type(2)));

// Coefficients live in static device memory: d_ws is never touched.
// Layout: per freq i: g_fr[i] = freq/2pi; g_P[i] = (phase_x, phase_y) in revs;
// g_R[i] = (amp_x, amp_y). Phase-folded A sin+B cos = R sin(th+phi).
__device__ float g_fr[NFREQ];
__device__ v2f   g_P[NFREQ];
__device__ v2f   g_R[NFREQ];

__device__ __forceinline__ v2f mkv2(float a, float b) { v2f r; r.x = a; r.y = b; return r; }

// ---------------------------------------------------------------------------
// init: zero the int32 accumulators (out buffer) AND compute the 50 folded
// coefficients in block 0 (saves one dispatch vs separate coeff kernel).
// ---------------------------------------------------------------------------
__global__ __launch_bounds__(256) void init_kernel(int* __restrict__ acc, int total,
                                                   const float* __restrict__ freqs,
                                                   const float* __restrict__ weight) {
    if (blockIdx.x == 0 && threadIdx.x < NFREQ) {
        int i = threadIdx.x;
        g_fr[i] = freqs[2 * i] * INV2PI;
        float A0 = weight[2 * i],             B0 = weight[2 * i + 1];
        float A1 = weight[2 * NFREQ + 2 * i], B1 = weight[2 * NFREQ + 2 * i + 1];
        g_R[i] = mkv2(sqrtf(A0 * A0 + B0 * B0), sqrtf(A1 * A1 + B1 * B1));
        g_P[i] = mkv2(atan2f(B0, A0) * INV2PI, atan2f(B1, A1) * INV2PI);
    }
    int b = (blockIdx.x * blockDim.x + threadIdx.x) * 4;
    if (b + 3 < total) {
        *(int4*)(acc + b) = make_int4(0, 0, 0, 0);
    } else {
        for (int k = 0; k < 4; ++k)
            if (b + k < total) acc[b + k] = 0;
    }
}

// Packed (x,y) evaluation: v2f ops encourage v_pk_fma_f32; 20 sins/frag-pair
// stay scalar (v_sin_f32, input in revolutions).
__device__ __forceinline__ float frag_eval(v2f c, const float* __restrict__ fr,
                                           const v2f* __restrict__ P,
                                           const v2f* __restrict__ R) {
    v2f acc = mkv2(0.f, 0.f);
#pragma unroll
    for (int i = 0; i < NFREQ; ++i) {
        v2f th = c * fr[i] + P[i];
        v2f s;
        s.x = __builtin_amdgcn_sinf(th.x);
        s.y = __builtin_amdgcn_sinf(th.y);
        acc += R[i] * s;
    }
    return acc.x + acc.y;
}

// ---------------------------------------------------------------------------
// Two fragments per thread. Pure pairs (same key) merge locally; the wave
// then runs the standard 6-step segmented suffix scan keyed on each lane's
// FIRST key (sorted ix => if ka(l+d)==ka(l), every fragment in between has
// that key, so intermediate lanes are "pure" and their merged value is the
// full contribution — the doubling recursion is unchanged). Impure lanes
// additionally own the head of their SECOND key's run: its total is
// sb + v(l+1) if lane l+1 continues it (one extra post-scan shuffle).
// All partials go in as int32 fixed-point atomics -> bit-deterministic.
// ---------------------------------------------------------------------------
__global__ __launch_bounds__(TPB) void scan_kernel(
        const float* __restrict__ coords,   // [F,2]
        const int*   __restrict__ ix,       // [F], sorted
        int* __restrict__ acc,              // [total] int32 accumulators (=out)
        int F) {
    float fr[NFREQ]; v2f P[NFREQ], R[NFREQ];
#pragma unroll
    for (int i = 0; i < NFREQ; ++i) {       // uniform -> scalar loads
        fr[i] = g_fr[i]; P[i] = g_P[i]; R[i] = g_R[i];
    }

    const int t  = blockIdx.x * TPB + threadIdx.x;
    const int f0 = 2 * t;
    const int lane = threadIdx.x & 63;

    int   ka = -2, kb = -3;                 // distinct sentinels for tail
    float sa = 0.f, sb = 0.f;
    if (f0 + 1 < F) {
        int2   k2 = *(const int2*)(ix + f0);
        float4 c4 = *(const float4*)(coords + 2 * f0);
        ka = k2.x; kb = k2.y;
        sa = frag_eval(mkv2(c4.x, c4.y), fr, P, R);
        sb = frag_eval(mkv2(c4.z, c4.w), fr, P, R);
    } else if (f0 < F) {
        ka = ix[f0];
        float2 c2 = *(const float2*)(coords + 2 * f0);
        sa = frag_eval(mkv2(c2.x, c2.y), fr, P, R);
    }

    const bool pure = (ka == kb);
    float v = pure ? (sa + sb) : sa;        // contribution to ka's run

#pragma unroll
    for (int d = 1; d < 64; d <<= 1) {
        float ov = __shfl_down(v, d);
        int   ok = __shfl_down(ka, d);
        if (lane + d < 64 && ok == ka) v += ov;
    }

    // post-scan neighbor (for the second-run total of impure lanes)
    const float nv  = __shfl_down(v, 1);
    const int   nk  = __shfl_down(ka, 1);
    const int   pkb = __shfl_up(kb, 1);     // previous lane's LAST key

    const bool headA = (ka >= 0) && (lane == 0 || ka != pkb);
    if (headA)
        atomicAdd(acc + ka, __float2int_rn(v * SCALE_F));

    if (kb >= 0 && !pure) {                 // lane owns the head of kb's run
        float tb = sb + ((lane < 63 && nk == kb) ? nv : 0.f);
        atomicAdd(acc + kb, __float2int_rn(tb * SCALE_F));
    }
}

// ---------------------------------------------------------------------------
// out[b] = bias[gix[b % gene_n]] + acc[b] * 2^-20, in place.
// ---------------------------------------------------------------------------
__global__ __launch_bounds__(256) void finish_kernel(
        float* out, const float* __restrict__ bias,
        const int* __restrict__ gix, int gene_n, int total) {
    int b = (blockIdx.x * blockDim.x + threadIdx.x) * 4;
    if ((gene_n & 3) == 0 && b + 3 < total) {
        int4 a = *(const int4*)((const int*)out + b);
        int g = b % gene_n;
        float4 r;
        r.x = bias[gix[g]]     + (float)a.x * INV_SCALE;
        r.y = bias[gix[g + 1]] + (float)a.y * INV_SCALE;
        r.z = bias[gix[g + 2]] + (float)a.z * INV_SCALE;
        r.w = bias[gix[g + 3]] + (float)a.w * INV_SCALE;
        *(float4*)(out + b) = r;
    } else {
        for (int k = 0; k < 4; ++k) {
            int j = b + k;
            if (j < total) {
                int aj = ((const int*)out)[j];
                out[j] = bias[gix[j % gene_n]] + (float)aj * INV_SCALE;
            }
        }
    }
}

extern "C" void kernel_launch(void* const* d_in, const int* in_sizes, int n_in,
                              void* d_out, int out_size, void* d_ws, size_t ws_size,
                              hipStream_t stream) {
    const float* coords  = (const float*)d_in[0];
    const int*   ix      = (const int*)d_in[1];
    const int*   gene_ix = (const int*)d_in[4];
    const float* freqs   = (const float*)d_in[5];
    const float* weight  = (const float*)d_in[7];
    const float* bias    = (const float*)d_in[8];
    float* out = (float*)d_out;

    int F      = in_sizes[1];
    int gene_n = in_sizes[4];
    int total  = out_size;

    (void)d_ws; (void)ws_size; (void)n_in;

    int zthreads = (total + 3) / 4;
    hipLaunchKernelGGL(init_kernel, dim3((zthreads + 255) / 256), dim3(256),
                       0, stream, (int*)out, total, freqs, weight);

    int blocks = (F + TPB * FPT - 1) / (TPB * FPT);
    hipLaunchKernelGGL(scan_kernel, dim3(blocks), dim3(TPB), 0, stream,
                       coords, ix, (int*)out, F);

    hipLaunchKernelGGL(finish_kernel, dim3((zthreads + 255) / 256), dim3(256),
                       0, stream, out, bias, gene_ix, gene_n, total);
}